// Round 7
// baseline (538.937 us; speedup 1.0000x reference)
//
#include <hip/hip_runtime.h>
#include <stdint.h>

#define NE 50000   // entities
#define DD 128     // dim
#define RR 16      // relations
#define EE 50000   // edges per relation
#define NT 64      // node tile per block (4 waves x 16 nodes)
#define NTOT (RR * NE)                 // 800000 flat (n,r) keys, node-major
#define SCAN_BLK 4096
#define NSCAN ((NTOT + SCAN_BLK - 1) / SCAN_BLK)   // 196

typedef short  shortx8 __attribute__((ext_vector_type(8)));
typedef short  shortx4 __attribute__((ext_vector_type(4)));
typedef float  floatx4 __attribute__((ext_vector_type(4)));

__device__ __forceinline__ unsigned short f2bf(float f) {
    unsigned u = __float_as_uint(f);
    u += 0x7fffu + ((u >> 16) & 1u);   // RNE
    return (unsigned short)(u >> 16);
}
__device__ __forceinline__ float bf2f(unsigned short h) {
    return __uint_as_float(((unsigned)h) << 16);
}

// ---- fused init: zero counts | rel_trans -> MFMA-fragment-ordered bf16 Tf | ent_emb -> bf16
// Tf: element T[r][row][k] at ((((r*8+(row>>4))*4+(k>>5))*64) + ((k>>3)&3)*16 + (row&15))*8 + (k&7)
#define ZB 782
#define TB 128
#define EB 6250
__global__ void prep_k(const float* __restrict__ rt, unsigned short* __restrict__ Tf,
                       const float4* __restrict__ emb, shortx4* __restrict__ embA,
                       int* __restrict__ counts) {
    int b = blockIdx.x, t = threadIdx.x;
    if (b < ZB) {
        int i4 = b * 256 + t;
        if (i4 < NTOT / 4) *(int4*)(counts + i4 * 4) = make_int4(0, 0, 0, 0);
    } else if (b < ZB + TB) {
        int c = (b - ZB) * 256 + t;          // chunk: 8 consecutive k of one (r,row)
        int r = c >> 11, row = (c >> 4) & 127, cb = c & 15;
        int kt = cb >> 2, qq = cb & 3, rg = row >> 4, m = row & 15;
        const float4* src = (const float4*)(rt + (size_t)c * 8);
        float4 v0 = src[0], v1 = src[1];
        shortx8 w;
        w[0] = (short)f2bf(v0.x); w[1] = (short)f2bf(v0.y);
        w[2] = (short)f2bf(v0.z); w[3] = (short)f2bf(v0.w);
        w[4] = (short)f2bf(v1.x); w[5] = (short)f2bf(v1.y);
        w[6] = (short)f2bf(v1.z); w[7] = (short)f2bf(v1.w);
        size_t idx = ((((size_t)r * 8 + rg) * 4 + kt) * 64 + qq * 16 + m) * 8;
        *(shortx8*)(Tf + idx) = w;
    } else {
        int i = (b - ZB - TB) * 256 + t;
        if (i < NE * DD / 4) {
            float4 v = emb[i];
            shortx4 w;
            w[0] = (short)f2bf(v.x); w[1] = (short)f2bf(v.y);
            w[2] = (short)f2bf(v.z); w[3] = (short)f2bf(v.w);
            embA[i] = w;
        }
    }
}

// key = node*RR + r (node-major). Saves per-edge bucket rank so fill needs no atomics.
__global__ void hist_k(const int* __restrict__ erow, int* __restrict__ counts,
                       uchar4* __restrict__ rank) {
    int r  = blockIdx.y;
    int i4 = blockIdx.x * 256 + threadIdx.x;
    if (i4 < EE / 4) {
        int4 rw = *(const int4*)(erow + (size_t)r * EE + i4 * 4);
        uchar4 rk;
        rk.x = (unsigned char)atomicAdd(&counts[rw.x * RR + r], 1);
        rk.y = (unsigned char)atomicAdd(&counts[rw.y * RR + r], 1);
        rk.z = (unsigned char)atomicAdd(&counts[rw.z * RR + r], 1);
        rk.w = (unsigned char)atomicAdd(&counts[rw.w * RR + r], 1);
        rank[(size_t)r * (EE / 4) + i4] = rk;
    }
}

__global__ void scanA(const int* __restrict__ c, int* __restrict__ bsum) {
    int b = blockIdx.x, t = threadIdx.x;
    int base = b * SCAN_BLK + t * 16;
    int s = 0;
    #pragma unroll
    for (int i = 0; i < 16; i++) {
        int idx = base + i;
        if (idx < NTOT) s += c[idx];
    }
    __shared__ int sh[256];
    sh[t] = s;
    __syncthreads();
    for (int off = 128; off > 0; off >>= 1) {
        if (t < off) sh[t] += sh[t + off];
        __syncthreads();
    }
    if (t == 0) bsum[b] = sh[0];
}

// scanC derives its own block prefix from raw bsum (scanB folded in).
__global__ void scanC(const int* __restrict__ counts, int* __restrict__ rp,
                      const int* __restrict__ bsum) {
    int b = blockIdx.x, t = threadIdx.x;
    __shared__ int shb[256];
    shb[t] = (t < NSCAN) ? bsum[t] : 0;
    __syncthreads();
    for (int off = 1; off < 256; off <<= 1) {
        int add = (t >= off) ? shb[t - off] : 0;
        __syncthreads();
        shb[t] += add;
        __syncthreads();
    }
    int blockPrefix = (b > 0) ? shb[b - 1] : 0;
    int base = b * SCAN_BLK + t * 16;
    int vals[16];
    int s = 0;
    #pragma unroll
    for (int i = 0; i < 16; i++) {
        int idx = base + i;
        vals[i] = (idx < NTOT) ? counts[idx] : 0;
        s += vals[i];
    }
    __shared__ int sh[256];
    sh[t] = s;
    __syncthreads();
    for (int off = 1; off < 256; off <<= 1) {
        int add = (t >= off) ? sh[t - off] : 0;
        __syncthreads();
        sh[t] += add;
        __syncthreads();
    }
    int run = blockPrefix + sh[t] - s;
    #pragma unroll
    for (int i = 0; i < 16; i++) {
        int idx = base + i;
        if (idx < NTOT) {
            rp[idx] = run;
            run += vals[i];
            if (idx == NTOT - 1) rp[NTOT] = run;
        }
    }
}

// atomic-free placement: pos = rp[key] + saved rank
__global__ void fill_k(const int* __restrict__ erow, const int* __restrict__ ecol,
                       const float* __restrict__ eval, const int* __restrict__ rp,
                       const uchar4* __restrict__ rank, int2* __restrict__ edges) {
    int r  = blockIdx.y;
    int i4 = blockIdx.x * 256 + threadIdx.x;
    if (i4 < EE / 4) {
        int4   rw = *(const int4*)(erow + (size_t)r * EE + i4 * 4);
        int4   cl = *(const int4*)(ecol + (size_t)r * EE + i4 * 4);
        float4 vl = *(const float4*)(eval + (size_t)r * EE + i4 * 4);
        uchar4 rk = rank[(size_t)r * (EE / 4) + i4];
        edges[rp[rw.x * RR + r] + rk.x] = make_int2(cl.x, __float_as_int(vl.x));
        edges[rp[rw.y * RR + r] + rk.y] = make_int2(cl.y, __float_as_int(vl.y));
        edges[rp[rw.z * RR + r] + rk.z] = make_int2(cl.z, __float_as_int(vl.z));
        edges[rp[rw.w * RR + r] + rk.w] = make_int2(cl.w, __float_as_int(vl.w));
    }
}

// Fused layer, WAVE-PRIVATE: each wave owns 16 nodes and ALL 128 output rows.
// Lane (nl=lane&15, qq=lane>>4) gathers EXACTLY its MFMA B-fragment dims
// (kt*32 + qq*8 + 0..7) for node nl -> S accumulates in registers, packs
// directly to B-frags. NO LDS, NO BARRIERS in the whole kernel: waves are
// fully independent streams (R6 showed barrier lockstep, not occupancy, was
// the wall). Per relation: FMA 2 inline edges (+rare serial tail c>2), pack,
// prefetch r+1 chain (rp/eg L1-hot after r=0; row loads ~700cy fly under the
// ~600cy MFMA phase - wave-private, no barrier to cross, ~16 regs in flight).
// A-frags from L2-resident Tf, one row-tile prefetched ahead.
template<bool FINAL>
__global__ __launch_bounds__(256, 3)
void layer_k(const unsigned short* __restrict__ embIn,
             const unsigned short* __restrict__ Tf,
             const int* __restrict__ rp,
             const int2* __restrict__ eg,
             unsigned short* __restrict__ embOut,
             float* __restrict__ outF)
{
    const int t    = threadIdx.x;
    const int lane = t & 63;
    const int wv   = t >> 6;            // wave 0..3
    const int nl   = lane & 15;         // node within wave's group
    const int qq   = lane >> 4;         // dim-chunk / row-quad (0..3)
    const int n    = blockIdx.x * NT + wv * 16 + nl;
    const bool ok  = n < NE;
    const int key0 = (ok ? n : NE - 1) * RR;

    floatx4 acc[8];
    #pragma unroll
    for (int i = 0; i < 8; i++) acc[i] = (floatx4){0.f, 0.f, 0.f, 0.f};

    // 2-phase meta + in-flight row registers (compile-time phase indices only)
    int   sM[2], cM[2];
    float v0M[2], v1M[2];
    shortx8 m0[2][4], m1[2][4];

    // prologue: chain for r=0 into phase 0 (exposed once)
    {
        int a = rp[key0], b = rp[key0 + 1];
        int cnt = ok ? (b - a) : 0;
        sM[0] = a; cM[0] = cnt;
        int2 E0 = eg[a], E1 = eg[a + 1];     // +8 pad covers overread
        int col0 = cnt > 0 ? E0.x : 0;
        int col1 = cnt > 1 ? E1.x : col0;
        v0M[0] = cnt > 0 ? __int_as_float(E0.y) : 0.f;
        v1M[0] = cnt > 1 ? __int_as_float(E1.y) : 0.f;
        const unsigned short* r0 = embIn + (size_t)col0 * DD + qq * 8;
        const unsigned short* r1 = embIn + (size_t)col1 * DD + qq * 8;
        #pragma unroll
        for (int kt = 0; kt < 4; kt++) {
            m0[0][kt] = *(const shortx8*)(r0 + kt * 32);
            m1[0][kt] = *(const shortx8*)(r1 + kt * 32);
        }
    }

    auto body = [&](int r, int ph) {
        const int pn = ph ^ 1;
        // ---- FMA current relation into f32 accum (B-frag dim order)
        float aS[32];
        #pragma unroll
        for (int kt = 0; kt < 4; kt++)
            #pragma unroll
            for (int j = 0; j < 8; j++)
                aS[kt * 8 + j] = fmaf(v0M[ph], bf2f((unsigned short)m0[ph][kt][j]),
                                      v1M[ph] * bf2f((unsigned short)m1[ph][kt][j]));
        // rare serial tail (c>2): edge words L1-hot (node's span = 1-2 lines)
        if (cM[ph] > 2) {
            int s = sM[ph];
            #pragma unroll 1
            for (int k = s + 2; k < s + cM[ph]; k++) {
                int2 E = eg[k];
                float v = __int_as_float(E.y);
                const unsigned short* rw = embIn + (size_t)E.x * DD + qq * 8;
                #pragma unroll
                for (int kt = 0; kt < 4; kt++) {
                    shortx8 mm = *(const shortx8*)(rw + kt * 32);
                    #pragma unroll
                    for (int j = 0; j < 8; j++)
                        aS[kt * 8 + j] = fmaf(v, bf2f((unsigned short)mm[j]), aS[kt * 8 + j]);
                }
            }
        }
        // ---- pack to bf16 B-frags
        shortx8 bf[4];
        #pragma unroll
        for (int kt = 0; kt < 4; kt++)
            #pragma unroll
            for (int j = 0; j < 8; j++)
                bf[kt][j] = (short)f2bf(aS[kt * 8 + j]);

        // ---- prefetch chain for r+1 (wave-private; covered by MFMA below)
        if (r < 15) {
            int a = rp[key0 + r + 1], b = rp[key0 + r + 2];
            int cnt = ok ? (b - a) : 0;
            sM[pn] = a; cM[pn] = cnt;
            int2 E0 = eg[a], E1 = eg[a + 1];
            int col0 = cnt > 0 ? E0.x : 0;
            int col1 = cnt > 1 ? E1.x : col0;
            v0M[pn] = cnt > 0 ? __int_as_float(E0.y) : 0.f;
            v1M[pn] = cnt > 1 ? __int_as_float(E1.y) : 0.f;
            const unsigned short* r0 = embIn + (size_t)col0 * DD + qq * 8;
            const unsigned short* r1 = embIn + (size_t)col1 * DD + qq * 8;
            #pragma unroll
            for (int kt = 0; kt < 4; kt++) {
                m0[pn][kt] = *(const shortx8*)(r0 + kt * 32);
                m1[pn][kt] = *(const shortx8*)(r1 + kt * 32);
            }
        }
        __builtin_amdgcn_sched_barrier(0);   // pin prefetch issue above the MFMAs

        // ---- MFMA: 8 row-tiles x 4 kt; A-frags from L2 Tf, one tile ahead
        const unsigned short* tb = Tf + (size_t)r * 8 * 4 * 64 * 8;
        shortx8 af[2][4];
        #pragma unroll
        for (int kt = 0; kt < 4; kt++)
            af[0][kt] = *(const shortx8*)(tb + ((size_t)(0 * 4 + kt) * 64 + lane) * 8);
        #pragma unroll
        for (int tt = 0; tt < 8; tt++) {
            const int cur = tt & 1, nxt = cur ^ 1;
            if (tt < 7) {
                #pragma unroll
                for (int kt = 0; kt < 4; kt++)
                    af[nxt][kt] = *(const shortx8*)(tb + ((size_t)((tt + 1) * 4 + kt) * 64 + lane) * 8);
            }
            #pragma unroll
            for (int kt = 0; kt < 4; kt++)
                acc[tt] = __builtin_amdgcn_mfma_f32_16x16x32_bf16(af[cur][kt], bf[kt], acc[tt], 0, 0, 0);
        }
    };

    #pragma unroll 1
    for (int h = 0; h < 8; h++) {
        body(2 * h,     0);
        body(2 * h + 1, 1);
    }

    // ---- epilogue: D tile tt -> rows tt*16+qq*4+g, col nl -> node n. No LDS:
    // L2-norm reduces across the 4 qq-lanes of each node via shfl_xor(16/32).
    if (!FINAL) {
        if (ok) {
            #pragma unroll
            for (int tt = 0; tt < 8; tt++) {
                shortx4 wvx;
                #pragma unroll
                for (int g = 0; g < 4; g++) {
                    float v = acc[tt][g];
                    v = v > 0.f ? v : 0.f;
                    wvx[g] = (short)f2bf(v);
                }
                *(shortx4*)(embOut + ((size_t)n * DD + tt * 16 + qq * 4)) = wvx;
            }
        }
    } else {
        float ss = 0.f;
        #pragma unroll
        for (int tt = 0; tt < 8; tt++)
            #pragma unroll
            for (int g = 0; g < 4; g++) {
                float v = acc[tt][g];
                v = v > 0.f ? v : 0.f;
                acc[tt][g] = v;
                ss += v * v;
            }
        ss += __shfl_xor(ss, 16, 64);   // reduce over qq quads (lanes nl, nl+16, nl+32, nl+48)
        ss += __shfl_xor(ss, 32, 64);
        float scale = 1.f / fmaxf(sqrtf(ss), 1e-12f);
        if (ok) {
            #pragma unroll
            for (int tt = 0; tt < 8; tt++) {
                floatx4 v4;
                #pragma unroll
                for (int g = 0; g < 4; g++) v4[g] = acc[tt][g] * scale;
                *(floatx4*)(outF + ((size_t)n * DD + tt * 16 + qq * 4)) = v4;
            }
        }
    }
}

static inline size_t align256(size_t x) { return (x + 255) & ~(size_t)255; }

extern "C" void kernel_launch(void* const* d_in, const int* in_sizes, int n_in,
                              void* d_out, int out_size, void* d_ws, size_t ws_size,
                              hipStream_t stream)
{
    const float* ent_emb   = (const float*)d_in[0];   // [NE, DD] fp32
    const float* rel_trans = (const float*)d_in[1];   // [RR, DD, DD] fp32
    const float* edge_val  = (const float*)d_in[2];   // [RR, EE] fp32
    const int*   edge_row  = (const int*)d_in[3];     // [RR, EE] int32
    const int*   edge_col  = (const int*)d_in[4];     // [RR, EE] int32
    float* out = (float*)d_out;                       // [NE, DD] fp32

    char* ws = (char*)d_ws;
    size_t off = 0;
    int* counts = (int*)(ws + off);  off = align256(off + (size_t)NTOT * 4);
    int* rpf    = (int*)(ws + off);  off = align256(off + ((size_t)NTOT + 1) * 4);
    int* bsum   = (int*)(ws + off);  off = align256(off + 256 * 4);
    uchar4* rank = (uchar4*)(ws + off); off = align256(off + (size_t)NTOT);
    int2* edges = (int2*)(ws + off); off = align256(off + ((size_t)NTOT + 8) * 8);  // +pad for 2-edge overread
    unsigned short* Tf   = (unsigned short*)(ws + off); off = align256(off + (size_t)RR * DD * DD * 2);
    unsigned short* embA = (unsigned short*)(ws + off); off = align256(off + (size_t)NE * DD * 2);
    unsigned short* embB = (unsigned short*)(ws + off); off = align256(off + (size_t)NE * DD * 2);
    // total ~40 MB

    prep_k<<<ZB + TB + EB, 256, 0, stream>>>(rel_trans, Tf, (const float4*)ent_emb,
                                             (shortx4*)embA, counts);
    dim3 eg_grid((EE / 4 + 255) / 256, RR);
    hist_k<<<eg_grid, 256, 0, stream>>>(edge_row, counts, rank);
    scanA<<<NSCAN, 256, 0, stream>>>(counts, bsum);
    scanC<<<NSCAN, 256, 0, stream>>>(counts, rpf, bsum);
    fill_k<<<eg_grid, 256, 0, stream>>>(edge_row, edge_col, edge_val, rpf, rank, edges);

    int nb = (NE + NT - 1) / NT;  // 782
    layer_k<false><<<nb, 256, 0, stream>>>(embA, Tf, rpf, edges, embB, nullptr);
    layer_k<true ><<<nb, 256, 0, stream>>>(embB, Tf, rpf, edges, nullptr, out);
}